// Round 4
// baseline (190.813 us; speedup 1.0000x reference)
//
#include <hip/hip_runtime.h>
#include <math.h>

#define EPS 1e-6f
#define TAU 1.0f

#define TILE_BOXES 512            // boxes per tile
#define TILE_F4    640            // float4s per array per tile (512*5/4)
#define NBLOCKS    1024           // persistent blocks: 4/CU (LDS-bound)

// Full per-box loss. Same math as the verified v1-v4 kernels
// (passed absmax 3.9e-3 with __sincosf/__logf/__frcp_rn).
__device__ __forceinline__ float box_loss(float px, float py, float pw, float ph, float pr,
                                          float tx, float ty, float tw, float th, float tr) {
    pw = fminf(fmaxf(pw, 1e-7f), 1e7f);
    ph = fminf(fmaxf(ph, 1e-7f), 1e7f);
    tw = fminf(fmaxf(tw, 1e-7f), 1e7f);
    th = fminf(fmaxf(th, 1e-7f), 1e7f);

    float pa = 0.25f * pw * pw, pb = 0.25f * ph * ph;
    float ta = 0.25f * tw * tw, tb = 0.25f * th * th;

    float ps, pc, ts, tc;
    __sincosf(pr, &ps, &pc);
    __sincosf(tr, &ts, &tc);

    float p11 = pa * pc * pc + pb * ps * ps;
    float p12 = (pa - pb) * ps * pc;
    float p22 = pa * ps * ps + pb * pc * pc;
    float t11 = ta * tc * tc + tb * ts * ts;
    float t12 = (ta - tb) * ts * tc;
    float t22 = ta * ts * ts + tb * tc * tc;

    float det_p = p11 * p22 - p12 * p12;
    float det_t = t11 * t12 * 0.0f + t11 * t22 - t12 * t12;  // keep ordering simple

    float dx = px - tx;
    float dy = py - ty;

    float inv_det_t = __frcp_rn(det_t);
    float term1 = (t22 * dx * dx - 2.0f * t12 * dx * dy + t11 * dy * dy) * inv_det_t;
    float trace_term = (t22 * p11 - 2.0f * t12 * p12 + t11 * p22) * inv_det_t;
    float term2 = trace_term + __logf(det_t) - __logf(det_p);

    float dis = term1 + term2 - 2.0f;
    float kl = fmaxf(dis, EPS);
    return 1.0f - __frcp_rn(TAU + sqrtf(kl));
}

// Persistent 2-phase pipeline: double-buffered LDS tiles, staged via
// global_load_lds width=16 (wave-uniform LDS base + lane*16 -- our layout is
// exactly linear, so the constraint is satisfied). One vmcnt(0)+barrier
// (__syncthreads) per tile; stage(t+1) issues BEFORE compute(t) so HBM
// latency hides under compute and waves stay alive across ~8 tiles.
__global__ void __launch_bounds__(256) gd_loss_pipe(
        const float4* __restrict__ pred4,
        const float4* __restrict__ tgt4,
        float* __restrict__ out, int ntiles) {
    __shared__ float sp[2][TILE_BOXES * 5];   // 10 KiB each
    __shared__ float st[2][TILE_BOXES * 5];   // total 40 KiB -> 4 blocks/CU

    const int t = threadIdx.x;

    auto stage = [&](int buf, int tile) {
        const float4* ps = pred4 + (size_t)tile * TILE_F4;
        const float4* ts = tgt4  + (size_t)tile * TILE_F4;
        #pragma unroll
        for (int k = t; k < TILE_F4; k += 256) {
            __builtin_amdgcn_global_load_lds(
                (const __attribute__((address_space(1))) void*)(ps + k),
                (__attribute__((address_space(3))) void*)(&sp[buf][k * 4]),
                16, 0, 0);
            __builtin_amdgcn_global_load_lds(
                (const __attribute__((address_space(1))) void*)(ts + k),
                (__attribute__((address_space(3))) void*)(&st[buf][k * 4]),
                16, 0, 0);
        }
    };

    int tile = blockIdx.x;
    if (tile >= ntiles) return;

    stage(0, tile);
    __syncthreads();              // drains vmcnt(0): buf0 ready

    int buf = 0;
    while (true) {
        int nxt = tile + NBLOCKS;
        if (nxt < ntiles) stage(buf ^ 1, nxt);   // issue next tile's loads first

        // compute current tile: thread handles boxes t and t+256.
        // LDS float-stride 5: bank (5t+j) mod 32, gcd(5,32)=1 -> 2 lanes/bank, free.
        #pragma unroll
        for (int k = 0; k < 2; ++k) {
            int b = t + k * 256;
            const float* p = &sp[buf][b * 5];
            const float* q = &st[buf][b * 5];
            out[(size_t)tile * TILE_BOXES + b] =
                box_loss(p[0], p[1], p[2], p[3], p[4],
                         q[0], q[1], q[2], q[3], q[4]);
        }

        if (nxt >= ntiles) break;
        __syncthreads();          // vmcnt(0)+barrier: next buf staged, cur buf free
        buf ^= 1;
        tile = nxt;
    }
}

// Scalar tail for n % 512 boxes.
__global__ void __launch_bounds__(64) gd_loss_tail(
        const float* __restrict__ pred,
        const float* __restrict__ tgt,
        float* __restrict__ out, int start, int n) {
    int i = start + blockIdx.x * blockDim.x + threadIdx.x;
    if (i >= n) return;
    const float* p = pred + (size_t)i * 5;
    const float* t = tgt  + (size_t)i * 5;
    out[i] = box_loss(p[0], p[1], p[2], p[3], p[4],
                      t[0], t[1], t[2], t[3], t[4]);
}

extern "C" void kernel_launch(void* const* d_in, const int* in_sizes, int n_in,
                              void* d_out, int out_size, void* d_ws, size_t ws_size,
                              hipStream_t stream) {
    const float* pred = (const float*)d_in[0];
    const float* tgt  = (const float*)d_in[1];
    float* out = (float*)d_out;
    int n = out_size;  // N boxes, one loss per box

    int ntiles = n / TILE_BOXES;          // full tiles
    int rem = n - ntiles * TILE_BOXES;

    if (ntiles > 0) {
        int grid = ntiles < NBLOCKS ? ntiles : NBLOCKS;
        gd_loss_pipe<<<grid, 256, 0, stream>>>(
            (const float4*)pred, (const float4*)tgt, out, ntiles);
    }
    if (rem > 0) {
        int grid = (rem + 63) / 64;
        gd_loss_tail<<<grid, 64, 0, stream>>>(pred, tgt, out, ntiles * TILE_BOXES, n);
    }
}

// Round 6
// 188.010 us; speedup vs baseline: 1.0149x; 1.0149x over previous
//
#include <hip/hip_runtime.h>
#include <math.h>

#define EPS 1e-6f
#define TAU 1.0f

typedef float nfloat4 __attribute__((ext_vector_type(4)));  // native vec for nontemporal builtin

// Full per-box loss. Same math as the verified v1-v5 kernels
// (passed absmax 3.9e-3 with __sincosf/__logf/__frcp_rn).
__device__ __forceinline__ float box_loss(float px, float py, float pw, float ph, float pr,
                                          float tx, float ty, float tw, float th, float tr) {
    pw = fminf(fmaxf(pw, 1e-7f), 1e7f);
    ph = fminf(fmaxf(ph, 1e-7f), 1e7f);
    tw = fminf(fmaxf(tw, 1e-7f), 1e7f);
    th = fminf(fmaxf(th, 1e-7f), 1e7f);

    float pa = 0.25f * pw * pw, pb = 0.25f * ph * ph;
    float ta = 0.25f * tw * tw, tb = 0.25f * th * th;

    float ps, pc, ts, tc;
    __sincosf(pr, &ps, &pc);
    __sincosf(tr, &ts, &tc);

    float p11 = pa * pc * pc + pb * ps * ps;
    float p12 = (pa - pb) * ps * pc;
    float p22 = pa * ps * ps + pb * pc * pc;
    float t11 = ta * tc * tc + tb * ts * ts;
    float t12 = (ta - tb) * ts * tc;
    float t22 = ta * ts * ts + tb * tc * tc;

    float det_p = p11 * p22 - p12 * p12;
    float det_t = t11 * t22 - t12 * t12;

    float dx = px - tx;
    float dy = py - ty;

    float inv_det_t = __frcp_rn(det_t);
    float term1 = (t22 * dx * dx - 2.0f * t12 * dx * dy + t11 * dy * dy) * inv_det_t;
    float trace_term = (t22 * p11 - 2.0f * t12 * p12 + t11 * p22) * inv_det_t;
    float term2 = trace_term + __logf(det_t) - __logf(det_p);

    float dis = term1 + term2 - 2.0f;
    float kl = fmaxf(dis, EPS);
    return 1.0f - __frcp_rn(TAU + sqrtf(kl));
}

// Barrier-free persistent grid-stride loop -- the exact structure of the
// kernels that set this chip's measured BW ceilings (m13 copy, m146 RMSNorm).
// Waves live for the whole kernel; no syncthreads / vmcnt(0) drains anywhere;
// the compiler pipelines iteration i+1's 10 float4 loads under iteration i's
// math. Output uses a nontemporal store (never re-read; keep L3 for inputs).
__global__ void __launch_bounds__(256) gd_loss_stream(
        const float4* __restrict__ pred4,
        const float4* __restrict__ tgt4,
        nfloat4* __restrict__ out4, int n4) {   // n4 = groups of 4 boxes
    const int stride = gridDim.x * blockDim.x;
    for (int i = blockIdx.x * blockDim.x + threadIdx.x; i < n4; i += stride) {
        const float4* p = pred4 + (size_t)i * 5;   // 80 B/group, 16 B aligned
        const float4* t = tgt4  + (size_t)i * 5;

        float4 a0 = p[0], a1 = p[1], a2 = p[2], a3 = p[3], a4 = p[4];
        float4 b0 = t[0], b1 = t[1], b2 = t[2], b3 = t[3], b4 = t[4];

        nfloat4 r;
        r.x = box_loss(a0.x, a0.y, a0.z, a0.w, a1.x,
                       b0.x, b0.y, b0.z, b0.w, b1.x);
        r.y = box_loss(a1.y, a1.z, a1.w, a2.x, a2.y,
                       b1.y, b1.z, b1.w, b2.x, b2.y);
        r.z = box_loss(a2.z, a2.w, a3.x, a3.y, a3.z,
                       b2.z, b2.w, b3.x, b3.y, b3.z);
        r.w = box_loss(a3.w, a4.x, a4.y, a4.z, a4.w,
                       b3.w, b4.x, b4.y, b4.z, b4.w);

        __builtin_nontemporal_store(r, &out4[i]);
    }
}

// Scalar tail for n % 4 boxes (not hit at N = 4,000,000; defensive).
__global__ void __launch_bounds__(64) gd_loss_tail(
        const float* __restrict__ pred,
        const float* __restrict__ tgt,
        float* __restrict__ out, int start, int n) {
    int i = start + blockIdx.x * blockDim.x + threadIdx.x;
    if (i >= n) return;
    const float* p = pred + (size_t)i * 5;
    const float* t = tgt  + (size_t)i * 5;
    out[i] = box_loss(p[0], p[1], p[2], p[3], p[4],
                      t[0], t[1], t[2], t[3], t[4]);
}

extern "C" void kernel_launch(void* const* d_in, const int* in_sizes, int n_in,
                              void* d_out, int out_size, void* d_ws, size_t ws_size,
                              hipStream_t stream) {
    const float* pred = (const float*)d_in[0];
    const float* tgt  = (const float*)d_in[1];
    float* out = (float*)d_out;
    int n = out_size;  // N boxes, one loss per box

    int n4 = n >> 2;
    int rem = n & 3;

    if (n4 > 0) {
        // 2048 blocks: 8 blocks/CU at 256 CUs (full 32-wave residency),
        // ~2 grid-stride iterations per thread at N=4M.
        int block = 256;
        int grid = 2048;
        int needed = (n4 + block - 1) / block;
        if (grid > needed) grid = needed;
        gd_loss_stream<<<grid, block, 0, stream>>>(
            (const float4*)pred, (const float4*)tgt, (nfloat4*)out, n4);
    }
    if (rem > 0) {
        gd_loss_tail<<<1, 64, 0, stream>>>(pred, tgt, out, n4 << 2, n);
    }
}